// Round 5
// baseline (166.000 us; speedup 1.0000x reference)
//
#include <hip/hip_runtime.h>
#include <stdint.h>

typedef unsigned long long u64;
typedef unsigned int u32;

#define BATCH   8
#define TOTAL   21824
#define NCLS    80
#define NDET    100
#define IMGSZ   1024.0f
#define STHR    0.2f
#define NMST    0.6f
#define NBUCK   4096        /* monotone score buckets */
#define BMAX    4031        /* last bucket reachable by valid scores (clamped) */
#define KGLOB   1000        /* global top-K prefix (== min per-level k) */
#define NLOC    22          /* ceil(TOTAL/1024) per-thread cached scores */
#define PRE     1024        /* precomputed sorted-prefix boxes in LDS */
#define NBLK    86          /* score blocks per batch (256 rows each) */
#define DSTRIDE 8           /* done-counter stride (32B) to avoid false sharing */
#define ZN      ((BATCH * NBUCK + 64) / 4)   /* uint4 count to zero (hist + done + pad) */

__device__ __forceinline__ float sigm(float x) { return 1.0f / (1.0f + expf(-x)); }

// Order-preserving map: ascending km == descending score.
__device__ __forceinline__ u32 mapKm(float s) {
    u32 u = __float_as_uint(s);
    u32 m = u ^ ((u & 0x80000000u) ? 0xFFFFFFFFu : 0x80000000u);
    return ~m;
}
// Inverse for positive floats (all scattered scores are > 0.2):
__device__ __forceinline__ float unmapKm(u32 km) {
    return __uint_as_float((~km) ^ 0x80000000u);
}
// Composite key: ascending u64 == (score desc, anchor idx asc).
__device__ __forceinline__ u64 makeKey(float s, u32 idx) {
    return (((u64)mapKm(s)) << 32) | (u64)idx;
}

// Monotone bucket for VALID scores (>0.2): clamped to [0, BMAX].
__device__ __forceinline__ int bucketOfV(float s) {
    int b = (int)(__fmul_rn(__fsub_rn(1.0f, s), 5040.0f));
    return b > BMAX ? BMAX : b;
}

// Bit-exact IoU suppression test (no FMA contraction).
__device__ __forceinline__ bool suppress(float4 a, float4 c) {
    float aa = __fmul_rn(fmaxf(__fsub_rn(a.z, a.x), 0.f), fmaxf(__fsub_rn(a.w, a.y), 0.f));
    float ac = __fmul_rn(fmaxf(__fsub_rn(c.z, c.x), 0.f), fmaxf(__fsub_rn(c.w, c.y), 0.f));
    float ltx = fmaxf(a.x, c.x), lty = fmaxf(a.y, c.y);
    float rbx = fminf(a.z, c.z), rby = fminf(a.w, c.w);
    float iw = fmaxf(__fsub_rn(rbx, ltx), 0.f), ih = fmaxf(__fsub_rn(rby, lty), 0.f);
    float inter = __fmul_rn(iw, ih);
    float uni = __fsub_rn(__fadd_rn(aa, ac), inter);
    float iou = __fdiv_rn(inter, fmaxf(uni, 1e-9f));
    return iou > NMST;
}

// ---------------- Kernel 0: zero per-batch histograms + done counters ----------------
__global__ __launch_bounds__(256) void zero_hist(u32* __restrict__ g) {
    int i = blockIdx.x * 256 + threadIdx.x;
    if (i < ZN) ((uint4*)g)[i] = make_uint4(0u, 0u, 0u, 0u);
}

// ---------------- Fused kernel: score phase -> last-block-per-batch NMS ----------------
__global__ __launch_bounds__(1024) void fused_kernel(
        const float* __restrict__ logits, const float* __restrict__ ctr,
        const float* __restrict__ reg, const float* __restrict__ anchors,
        float* __restrict__ mscore, int* __restrict__ mlabel,
        u32* __restrict__ ghist, u32* __restrict__ done,
        float* __restrict__ out) {
    __shared__ u64 skey[2048];      // bucket-radix sorted keys
    __shared__ float4 preB[PRE];    // class-offset boxes of sorted prefix
    __shared__ u32 curbuf[NBUCK];   // scatter cursors; ALIASED as preR after scatter
    __shared__ u32 waveSum[16], waveOff[16];
    __shared__ u32 sh_B, sh_m;
    __shared__ int s_count, sh_ticket;
    __shared__ float4 accB[NDET];   // class-offset boxes of accepted
    __shared__ float4 accR[NDET];   // raw boxes of accepted
    __shared__ float  accS[NDET];   // scores of accepted
    __shared__ int    accIdx[NDET]; // anchor indices of accepted (labels re-gathered at emit)
    __shared__ float4 wb[64], wraw[64];   // fallback window (Ew beyond PRE)
    __shared__ u64 wsup[64];
    __shared__ u64 sRej[16];

    const int b = blockIdx.y, tid = threadIdx.x;
    const int wave = tid >> 6, lane = tid & 63;
    const int g = lane >> 2, j = lane & 3;

    // ---------- phase 1: scores/labels/hist for my 256 rows ----------
    {
        int r = blockIdx.x * 256 + wave * 16 + g;
        bool valid = r < TOTAL;
        float best = -1e30f; int bi = 0;
        if (valid) {
            const float* rowp = logits + ((size_t)b * TOTAL + r) * NCLS + j * 4;
#pragma unroll
            for (int u = 0; u < 5; u++) {
                float4 v = *(const float4*)(rowp + u * 16);
                int c0 = u * 16 + j * 4;
                if (v.x > best) { best = v.x; bi = c0; }
                if (v.y > best) { best = v.y; bi = c0 + 1; }
                if (v.z > best) { best = v.z; bi = c0 + 2; }
                if (v.w > best) { best = v.w; bi = c0 + 3; }
            }
        }
        // merge 4 lanes of one row: max, tie -> lowest class index
#pragma unroll
        for (int off = 1; off <= 2; off <<= 1) {
            float ob = __shfl_xor(best, off);
            int obi = __shfl_xor(bi, off);
            if (ob > best || (ob == best && obi < bi)) { best = ob; bi = obi; }
        }
        if (valid && j == 0) {
            float c = ctr[(size_t)b * TOTAL + r];
            float sc = sqrtf(sigm(best) * sigm(c));
            bool pass = sc > STHR;
            mscore[(size_t)b * TOTAL + r] = pass ? sc : -1.0f;
            mlabel[(size_t)b * TOTAL + r] = bi;
            if (pass) atomicAdd(&ghist[(size_t)b * NBUCK + bucketOfV(sc)], 1u);
        }
    }

    // ---------- last-block election (release -> count -> acquire) ----------
    // __syncthreads drains all waves' vmem (compiler-inserted waitcnt), so the
    // block's stores are resident in this XCD's L2; tid0's device-scope release
    // fence writes back L2; the device-scope atomicAdd is the coherent point.
    __syncthreads();
    if (tid == 0) {
        __threadfence();
        sh_ticket = (int)atomicAdd(&done[(size_t)b * DSTRIDE], 1u);
    }
    __syncthreads();
    if (sh_ticket != NBLK - 1) return;
    __threadfence();   // acquire: invalidate stale caches before reading others' data

    // ---------- phase 2: NMS for batch b (this block only) ----------
    const float* ms = mscore + (size_t)b * TOTAL;
    const int* ml = mlabel + (size_t)b * TOTAL;
    const float4* anch4 = (const float4*)anchors;
    const float4* reg4 = ((const float4*)reg) + (size_t)b * TOTAL;

    // Bucket counts for this thread's four buckets (issued first).
    uint4 hv = ((const uint4*)(ghist + (size_t)b * NBUCK))[tid];

    // Register-resident score cache: fully unrolled, compile-time indices.
    float sv[NLOC];
#pragma unroll
    for (int k = 0; k < NLOC; k++) {
        int i = tid + (k << 10);
        sv[k] = (i < TOTAL) ? ms[i] : -1.0f;
    }

    // Scan: thread t owns buckets 4t..4t+3.
    u32 h0 = hv.x, h1 = hv.y, h2 = hv.z, h3 = hv.w;
    u32 s = h0 + h1 + h2 + h3;
    u32 incl = s;
    for (int o = 1; o < 64; o <<= 1) {
        u32 t2 = (u32)__shfl_up((int)incl, o);
        if (lane >= o) incl += t2;
    }
    if (lane == 63) waveSum[wave] = incl;
    __syncthreads();
    if (tid == 0) {
        u32 acc = 0;
#pragma unroll
        for (int w = 0; w < 16; w++) { waveOff[w] = acc; acc += waveSum[w]; }
        sh_m = acc;                       // default: all valid (if < KGLOB valid)
        sh_B = (u32)BMAX;                 // sentinel boundary
        s_count = 0;
    }
    __syncthreads();
    const u32 E = waveOff[wave] + incl - s;   // keys in buckets < 4*tid
    const u32 p1 = E + h0, p2 = p1 + h1, p3 = p2 + h2, p4 = p3 + h3;
    if      (E  < KGLOB && KGLOB <= p1) { sh_B = (u32)(4 * tid);     sh_m = p1; }
    else if (p1 < KGLOB && KGLOB <= p2) { sh_B = (u32)(4 * tid + 1); sh_m = p2; }
    else if (p2 < KGLOB && KGLOB <= p3) { sh_B = (u32)(4 * tid + 2); sh_m = p3; }
    else if (p3 < KGLOB && KGLOB <= p4) { sh_B = (u32)(4 * tid + 3); sh_m = p4; }
    curbuf[4 * tid]     = E;
    curbuf[4 * tid + 1] = p1;
    curbuf[4 * tid + 2] = p2;
    curbuf[4 * tid + 3] = p3;
    __syncthreads();
    const int Bstar = (int)sh_B;

    // Radix scatter — key goes directly to its bucket's slot range.
#pragma unroll
    for (int k = 0; k < NLOC; k++) {
        float s0 = sv[k];
        if (s0 > STHR) {
            int bk = bucketOfV(s0);
            if (bk <= Bstar) {
                int pos = (int)atomicAdd(&curbuf[bk], 1u);
                if (pos < 2048) skey[pos] = makeKey(s0, (u32)(tid + (k << 10)));
            }
        }
    }
    __syncthreads();
    // curbuf is dead from here on -> reuse its 16KB as preR.
    float4* preR = (float4*)curbuf;

    // Cleanup: insertion-sort each bucket's tiny segment (thread owns 4 buckets).
#pragma unroll
    for (int q = 0; q < 4; q++) {
        int bk = 4 * tid + q;
        u32 cnt = (q == 0) ? h0 : (q == 1) ? h1 : (q == 2) ? h2 : h3;
        u32 lo0 = (q == 0) ? E  : (q == 1) ? p1 : (q == 2) ? p2 : p3;
        if (bk <= Bstar && cnt > 1) {
            int lo = (int)lo0;
            int hi = lo + (int)cnt; if (hi > 2048) hi = 2048;
            for (int i2 = lo + 1; i2 < hi; i2++) {
                u64 key = skey[i2];
                int j2 = i2 - 1;
                while (j2 >= lo && skey[j2] > key) { skey[j2 + 1] = skey[j2]; j2--; }
                skey[j2 + 1] = key;
            }
        }
    }
    __syncthreads();
    int m = (int)sh_m; if (m > 2048) m = 2048;
    const int Pm = m < PRE ? m : PRE;

    // Precompute boxes for the sorted prefix — ONE parallel gather round.
    for (int p = tid; p < Pm; p += 1024) {
        u64 key = skey[p];
        int idx = (int)(key & 0xFFFFFFFFu);
        float4 a = anch4[idx];
        float4 r = reg4[idx];
        int lb = ml[idx];
        float cx = (a.x + a.z) * 0.5f;
        float cy = (a.y + a.w) * 0.5f;
        float x1 = fminf(fmaxf(cx - r.x, 0.0f), IMGSZ);
        float y1 = fminf(fmaxf(cy - r.y, 0.0f), IMGSZ);
        float x2 = fminf(fmaxf(cx + r.z, 0.0f), IMGSZ);
        float y2 = fminf(fmaxf(cy + r.w, 0.0f), IMGSZ);
        float off = (float)lb * (IMGSZ + 1.0f);
        preR[p] = make_float4(x1, y1, x2, y2);
        preB[p] = make_float4(__fadd_rn(x1, off), __fadd_rn(y1, off),
                              __fadd_rn(x2, off), __fadd_rn(y2, off));
    }
    __syncthreads();

    // Windowed greedy NMS over the sorted prefix (LDS-resident fast path).
    int count = 0, Ew = 0;
    while (true) {
        int take = m - Ew; if (take > 64) take = 64;
        if (take <= 0) break;
        const bool ldsPath = (Ew + take <= Pm);

        if (!ldsPath) {
            // rare fallback: gather+compute this window into wb/wraw
            if (tid < take) {
                int idx = (int)(skey[Ew + tid] & 0xFFFFFFFFu);
                float4 a = anch4[idx];
                float4 r = reg4[idx];
                int lb = ml[idx];
                float cx = (a.x + a.z) * 0.5f;
                float cy = (a.y + a.w) * 0.5f;
                float x1 = fminf(fmaxf(cx - r.x, 0.0f), IMGSZ);
                float y1 = fminf(fmaxf(cy - r.y, 0.0f), IMGSZ);
                float x2 = fminf(fmaxf(cx + r.z, 0.0f), IMGSZ);
                float y2 = fminf(fmaxf(cy + r.w, 0.0f), IMGSZ);
                float off = (float)lb * (IMGSZ + 1.0f);
                wraw[tid] = make_float4(x1, y1, x2, y2);
                wb[tid] = make_float4(__fadd_rn(x1, off), __fadd_rn(y1, off),
                                      __fadd_rn(x2, off), __fadd_rn(y2, off));
            }
            __syncthreads();
        }

        // mask phase: rejection vs accepted set + intra-window pair masks
        {
            float4 myB;
            if (lane < take) myB = ldsPath ? preB[Ew + lane] : wb[lane];
            bool rej = false;
            if (lane < take) {
                for (int s2 = wave; s2 < count; s2 += 16) {
                    if (suppress(accB[s2], myB)) { rej = true; break; }
                }
            }
            u64 mask = __ballot(rej);
            if (lane == 0) sRej[wave] = mask;
            for (int rr = wave; rr < take; rr += 16) {
                float4 rB = ldsPath ? preB[Ew + rr] : wb[rr];
                bool sp = (lane < take && lane > rr) ? suppress(rB, myB) : false;
                u64 msk = __ballot(sp);
                if (lane == 0) wsup[rr] = msk;
            }
        }
        __syncthreads();

        // resolve (wave 0): union fast-path, else ctz-skipping greedy chain
        if (wave == 0) {
            u64 rj = (lane < 16) ? sRej[lane] : 0ull;
#pragma unroll
            for (int o = 1; o < 64; o <<= 1) rj |= __shfl_xor(rj, o);
            u64 supr = (lane < take) ? wsup[lane] : 0ull;
            u64 validb = (take >= 64) ? ~0ull : ((1ull << take) - 1ull);
            u64 aliveM = validb & ~rj;
            u64 contrib = ((aliveM >> lane) & 1ull) ? supr : 0ull;
            u64 U = contrib;
#pragma unroll
            for (int o = 1; o < 64; o <<= 1) U |= __shfl_xor(U, o);
            int space = NDET - count;
            u64 accM;
            if ((U & aliveM) == 0ull) {
                accM = aliveM;          // no alive element suppresses another
            } else {
                u64 rem = aliveM; accM = 0ull;
                while (rem) {
                    int rr = __builtin_ctzll(rem);
                    accM |= 1ull << rr;
                    if (__popcll(accM) >= space) break;   // further accepts never emitted
                    u64 sr = __shfl(supr, rr);
                    rem &= ~(1ull << rr);
                    rem &= ~sr;
                }
            }
            int na = __popcll(accM);
            int takeA = na < space ? na : space;
            if (lane < take && ((accM >> lane) & 1ull)) {
                int pos = __popcll(accM & ((1ull << lane) - 1ull));
                if (pos < takeA) {
                    int o2 = count + pos;
                    u64 key = skey[Ew + lane];
                    accB[o2] = ldsPath ? preB[Ew + lane] : wb[lane];
                    accR[o2] = ldsPath ? preR[Ew + lane] : wraw[lane];
                    accIdx[o2] = (int)(key & 0xFFFFFFFFu);
                    accS[o2] = unmapKm((u32)(key >> 32));
                }
            }
            if (lane == 0) s_count = count + takeA;
        }
        __syncthreads();
        count = s_count;
        Ew += take;
        if (count >= NDET) break;
    }
    __syncthreads();

    // emit top-100 (labels re-gathered, <=100 loads)
    for (int s2 = tid; s2 < NDET; s2 += 1024) {
        float4 bxv = make_float4(0.f, 0.f, 0.f, 0.f);
        float scv = 0.0f, lbv = -1.0f;
        if (s2 < count) {
            bxv = accR[s2];
            scv = accS[s2];
            lbv = (float)ml[accIdx[s2]];
        }
        ((float4*)out)[b * NDET + s2] = bxv;                                  // boxes [0,3200)
        out[BATCH * NDET * 4 + b * NDET + s2] = scv;                          // scores [3200,4000)
        out[BATCH * NDET * 4 + BATCH * NDET + b * NDET + s2] = lbv;           // labels [4000,4800)
    }
}

extern "C" void kernel_launch(void* const* d_in, const int* in_sizes, int n_in,
                              void* d_out, int out_size, void* d_ws, size_t ws_size,
                              hipStream_t stream) {
    (void)in_sizes; (void)n_in; (void)out_size; (void)ws_size;
    const float* logits  = (const float*)d_in[0];
    const float* reg     = (const float*)d_in[1];
    const float* ctr     = (const float*)d_in[2];
    const float* anchors = (const float*)d_in[3];
    float* out = (float*)d_out;

    char* ws = (char*)d_ws;
    size_t off = 0;
    auto alloc = [&](size_t bytes) -> void* {
        off = (off + 255) & ~(size_t)255;
        void* p = ws + off;
        off += bytes;
        return p;
    };
    float* mscore = (float*)alloc((size_t)BATCH * TOTAL * 4);
    int*   mlabel = (int*)  alloc((size_t)BATCH * TOTAL * 4);
    u32*   ghist  = (u32*)  alloc((size_t)(BATCH * NBUCK + 64) * 4);  // hist + done(strided) + pad
    u32*   done   = ghist + (size_t)BATCH * NBUCK;

    zero_hist<<<dim3((ZN + 255) / 256), 256, 0, stream>>>(ghist);
    fused_kernel<<<dim3(NBLK, BATCH), 1024, 0, stream>>>(
        logits, ctr, reg, anchors, mscore, mlabel, ghist, done, out);
}

// Round 6
// 149.977 us; speedup vs baseline: 1.1068x; 1.1068x over previous
//
#include <hip/hip_runtime.h>
#include <stdint.h>

typedef unsigned long long u64;
typedef unsigned int u32;

#define BATCH   8
#define TOTAL   21824
#define NCLS    80
#define NDET    100
#define IMGSZ   1024.0f
#define STHR    0.2f
#define NMST    0.6f
#define NBUCK   4096        /* monotone score buckets */
#define BMAX    4031        /* last bucket reachable by valid scores (clamped) */
#define KGLOB   1000        /* global top-K prefix (== min per-level k) */
#define NLOC    22          /* ceil(TOTAL/1024) per-thread cached scores */
#define PRE     1024        /* precomputed sorted-prefix boxes in LDS */
#define NBLK    86          /* score blocks per batch (256 rows each) */
#define DSTRIDE 8           /* done-counter stride (32B) to avoid false sharing */
#define ZN      ((BATCH * NBUCK + 64) / 4)   /* uint4 count to zero (hist + done + pad) */

__device__ __forceinline__ float sigm(float x) { return 1.0f / (1.0f + expf(-x)); }

// Order-preserving map: ascending km == descending score.
__device__ __forceinline__ u32 mapKm(float s) {
    u32 u = __float_as_uint(s);
    u32 m = u ^ ((u & 0x80000000u) ? 0xFFFFFFFFu : 0x80000000u);
    return ~m;
}
// Inverse for positive floats (all scattered scores are > 0.2):
__device__ __forceinline__ float unmapKm(u32 km) {
    return __uint_as_float((~km) ^ 0x80000000u);
}
// Composite key: ascending u64 == (score desc, anchor idx asc).
__device__ __forceinline__ u64 makeKey(float s, u32 idx) {
    return (((u64)mapKm(s)) << 32) | (u64)idx;
}

// Monotone bucket for VALID scores (>0.2): clamped to [0, BMAX].
__device__ __forceinline__ int bucketOfV(float s) {
    int b = (int)(__fmul_rn(__fsub_rn(1.0f, s), 5040.0f));
    return b > BMAX ? BMAX : b;
}

// Bit-exact IoU suppression test (no FMA contraction).
__device__ __forceinline__ bool suppress(float4 a, float4 c) {
    float aa = __fmul_rn(fmaxf(__fsub_rn(a.z, a.x), 0.f), fmaxf(__fsub_rn(a.w, a.y), 0.f));
    float ac = __fmul_rn(fmaxf(__fsub_rn(c.z, c.x), 0.f), fmaxf(__fsub_rn(c.w, c.y), 0.f));
    float ltx = fmaxf(a.x, c.x), lty = fmaxf(a.y, c.y);
    float rbx = fminf(a.z, c.z), rby = fminf(a.w, c.w);
    float iw = fmaxf(__fsub_rn(rbx, ltx), 0.f), ih = fmaxf(__fsub_rn(rby, lty), 0.f);
    float inter = __fmul_rn(iw, ih);
    float uni = __fsub_rn(__fadd_rn(aa, ac), inter);
    float iou = __fdiv_rn(inter, fmaxf(uni, 1e-9f));
    return iou > NMST;
}

// ---------------- Kernel 0: zero per-batch histograms + done counters ----------------
__global__ __launch_bounds__(256) void zero_hist(u32* __restrict__ g) {
    int i = blockIdx.x * 256 + threadIdx.x;
    if (i < ZN) ((uint4*)g)[i] = make_uint4(0u, 0u, 0u, 0u);
}

// ---------------- Fused kernel: score phase -> last-block-per-batch NMS ----------------
__global__ __launch_bounds__(1024) void fused_kernel(
        const float* __restrict__ logits, const float* __restrict__ ctr,
        const float* __restrict__ reg, const float* __restrict__ anchors,
        float* __restrict__ mscore, int* __restrict__ mlabel,
        u32* __restrict__ ghist, u32* __restrict__ done,
        float* __restrict__ out) {
    __shared__ u64 skey[2048];      // bucket-radix sorted keys
    __shared__ float4 preB[PRE];    // class-offset boxes of sorted prefix
    __shared__ u32 curbuf[NBUCK];   // scatter cursors; ALIASED as preR after scatter
    __shared__ u32 waveSum[16], waveOff[16];
    __shared__ u32 sh_B, sh_m;
    __shared__ int s_count, sh_ticket;
    __shared__ float4 accB[NDET];   // class-offset boxes of accepted
    __shared__ float4 accR[NDET];   // raw boxes of accepted
    __shared__ float  accS[NDET];   // scores of accepted
    __shared__ int    accIdx[NDET]; // anchor indices of accepted (labels re-gathered at emit)
    __shared__ float4 wb[64], wraw[64];   // fallback window (Ew beyond PRE)
    __shared__ u64 wsup[64];
    __shared__ u64 sRej[16];

    const int b = blockIdx.y, tid = threadIdx.x;
    const int wave = tid >> 6, lane = tid & 63;
    const int g = lane >> 2, j = lane & 3;

    // ---------- phase 1: scores/labels/hist for my 256 rows ----------
    {
        int r = blockIdx.x * 256 + wave * 16 + g;
        bool valid = r < TOTAL;
        float best = -1e30f; int bi = 0;
        if (valid) {
            const float* rowp = logits + ((size_t)b * TOTAL + r) * NCLS + j * 4;
#pragma unroll
            for (int u = 0; u < 5; u++) {
                float4 v = *(const float4*)(rowp + u * 16);
                int c0 = u * 16 + j * 4;
                if (v.x > best) { best = v.x; bi = c0; }
                if (v.y > best) { best = v.y; bi = c0 + 1; }
                if (v.z > best) { best = v.z; bi = c0 + 2; }
                if (v.w > best) { best = v.w; bi = c0 + 3; }
            }
        }
        // merge 4 lanes of one row: max, tie -> lowest class index
#pragma unroll
        for (int off = 1; off <= 2; off <<= 1) {
            float ob = __shfl_xor(best, off);
            int obi = __shfl_xor(bi, off);
            if (ob > best || (ob == best && obi < bi)) { best = ob; bi = obi; }
        }
        if (valid && j == 0) {
            float c = ctr[(size_t)b * TOTAL + r];
            float sc = sqrtf(sigm(best) * sigm(c));
            bool pass = sc > STHR;
            // Agent-scope coherent stores (global_store ... sc0 sc1): complete at
            // the device coherence point, so NO per-block L2 writeback fence is
            // needed for the election release. (Round-5 lesson: per-block
            // __threadfence() = 688 buffer_wbl2+inv -> 5x WRITE_SIZE, 335 GB/s.)
            __hip_atomic_store(&mscore[(size_t)b * TOTAL + r], pass ? sc : -1.0f,
                               __ATOMIC_RELAXED, __HIP_MEMORY_SCOPE_AGENT);
            __hip_atomic_store(&mlabel[(size_t)b * TOTAL + r], bi,
                               __ATOMIC_RELAXED, __HIP_MEMORY_SCOPE_AGENT);
            if (pass) atomicAdd(&ghist[(size_t)b * NBUCK + bucketOfV(sc)], 1u);
        }
    }

    // ---------- last-block election ----------
    // __syncthreads drains each wave's vmcnt; sc1 stores ack at the coherence
    // point, so after the barrier ALL of this block's results are device-visible.
    // The ticket atomic is agent-scope coherent -> relaxed add suffices.
    __syncthreads();
    if (tid == 0) {
        sh_ticket = (int)atomicAdd(&done[(size_t)b * DSTRIDE], 1u);
    }
    __syncthreads();
    if (sh_ticket != NBLK - 1) return;
    __threadfence();   // acquire (8 blocks total): invalidate stale L1/L2 lines
                       // (e.g. poison-fill copies) before reading others' data

    // ---------- phase 2: NMS for batch b (this block only) ----------
    const float* ms = mscore + (size_t)b * TOTAL;
    const int* ml = mlabel + (size_t)b * TOTAL;
    const float4* anch4 = (const float4*)anchors;
    const float4* reg4 = ((const float4*)reg) + (size_t)b * TOTAL;

    // Bucket counts for this thread's four buckets (issued first).
    uint4 hv = ((const uint4*)(ghist + (size_t)b * NBUCK))[tid];

    // Register-resident score cache: fully unrolled, compile-time indices.
    float sv[NLOC];
#pragma unroll
    for (int k = 0; k < NLOC; k++) {
        int i = tid + (k << 10);
        sv[k] = (i < TOTAL) ? ms[i] : -1.0f;
    }

    // Scan: thread t owns buckets 4t..4t+3.
    u32 h0 = hv.x, h1 = hv.y, h2 = hv.z, h3 = hv.w;
    u32 s = h0 + h1 + h2 + h3;
    u32 incl = s;
    for (int o = 1; o < 64; o <<= 1) {
        u32 t2 = (u32)__shfl_up((int)incl, o);
        if (lane >= o) incl += t2;
    }
    if (lane == 63) waveSum[wave] = incl;
    __syncthreads();
    if (tid == 0) {
        u32 acc = 0;
#pragma unroll
        for (int w = 0; w < 16; w++) { waveOff[w] = acc; acc += waveSum[w]; }
        sh_m = acc;                       // default: all valid (if < KGLOB valid)
        sh_B = (u32)BMAX;                 // sentinel boundary
        s_count = 0;
    }
    __syncthreads();
    const u32 E = waveOff[wave] + incl - s;   // keys in buckets < 4*tid
    const u32 p1 = E + h0, p2 = p1 + h1, p3 = p2 + h2, p4 = p3 + h3;
    if      (E  < KGLOB && KGLOB <= p1) { sh_B = (u32)(4 * tid);     sh_m = p1; }
    else if (p1 < KGLOB && KGLOB <= p2) { sh_B = (u32)(4 * tid + 1); sh_m = p2; }
    else if (p2 < KGLOB && KGLOB <= p3) { sh_B = (u32)(4 * tid + 2); sh_m = p3; }
    else if (p3 < KGLOB && KGLOB <= p4) { sh_B = (u32)(4 * tid + 3); sh_m = p4; }
    curbuf[4 * tid]     = E;
    curbuf[4 * tid + 1] = p1;
    curbuf[4 * tid + 2] = p2;
    curbuf[4 * tid + 3] = p3;
    __syncthreads();
    const int Bstar = (int)sh_B;

    // Radix scatter — key goes directly to its bucket's slot range.
#pragma unroll
    for (int k = 0; k < NLOC; k++) {
        float s0 = sv[k];
        if (s0 > STHR) {
            int bk = bucketOfV(s0);
            if (bk <= Bstar) {
                int pos = (int)atomicAdd(&curbuf[bk], 1u);
                if (pos < 2048) skey[pos] = makeKey(s0, (u32)(tid + (k << 10)));
            }
        }
    }
    __syncthreads();
    // curbuf is dead from here on -> reuse its 16KB as preR.
    float4* preR = (float4*)curbuf;

    // Cleanup: insertion-sort each bucket's tiny segment (thread owns 4 buckets).
#pragma unroll
    for (int q = 0; q < 4; q++) {
        int bk = 4 * tid + q;
        u32 cnt = (q == 0) ? h0 : (q == 1) ? h1 : (q == 2) ? h2 : h3;
        u32 lo0 = (q == 0) ? E  : (q == 1) ? p1 : (q == 2) ? p2 : p3;
        if (bk <= Bstar && cnt > 1) {
            int lo = (int)lo0;
            int hi = lo + (int)cnt; if (hi > 2048) hi = 2048;
            for (int i2 = lo + 1; i2 < hi; i2++) {
                u64 key = skey[i2];
                int j2 = i2 - 1;
                while (j2 >= lo && skey[j2] > key) { skey[j2 + 1] = skey[j2]; j2--; }
                skey[j2 + 1] = key;
            }
        }
    }
    __syncthreads();
    int m = (int)sh_m; if (m > 2048) m = 2048;
    const int Pm = m < PRE ? m : PRE;

    // Precompute boxes for the sorted prefix — ONE parallel gather round.
    for (int p = tid; p < Pm; p += 1024) {
        u64 key = skey[p];
        int idx = (int)(key & 0xFFFFFFFFu);
        float4 a = anch4[idx];
        float4 r = reg4[idx];
        int lb = ml[idx];
        float cx = (a.x + a.z) * 0.5f;
        float cy = (a.y + a.w) * 0.5f;
        float x1 = fminf(fmaxf(cx - r.x, 0.0f), IMGSZ);
        float y1 = fminf(fmaxf(cy - r.y, 0.0f), IMGSZ);
        float x2 = fminf(fmaxf(cx + r.z, 0.0f), IMGSZ);
        float y2 = fminf(fmaxf(cy + r.w, 0.0f), IMGSZ);
        float off = (float)lb * (IMGSZ + 1.0f);
        preR[p] = make_float4(x1, y1, x2, y2);
        preB[p] = make_float4(__fadd_rn(x1, off), __fadd_rn(y1, off),
                              __fadd_rn(x2, off), __fadd_rn(y2, off));
    }
    __syncthreads();

    // Windowed greedy NMS over the sorted prefix (LDS-resident fast path).
    int count = 0, Ew = 0;
    while (true) {
        int take = m - Ew; if (take > 64) take = 64;
        if (take <= 0) break;
        const bool ldsPath = (Ew + take <= Pm);

        if (!ldsPath) {
            // rare fallback: gather+compute this window into wb/wraw
            if (tid < take) {
                int idx = (int)(skey[Ew + tid] & 0xFFFFFFFFu);
                float4 a = anch4[idx];
                float4 r = reg4[idx];
                int lb = ml[idx];
                float cx = (a.x + a.z) * 0.5f;
                float cy = (a.y + a.w) * 0.5f;
                float x1 = fminf(fmaxf(cx - r.x, 0.0f), IMGSZ);
                float y1 = fminf(fmaxf(cy - r.y, 0.0f), IMGSZ);
                float x2 = fminf(fmaxf(cx + r.z, 0.0f), IMGSZ);
                float y2 = fminf(fmaxf(cy + r.w, 0.0f), IMGSZ);
                float off = (float)lb * (IMGSZ + 1.0f);
                wraw[tid] = make_float4(x1, y1, x2, y2);
                wb[tid] = make_float4(__fadd_rn(x1, off), __fadd_rn(y1, off),
                                      __fadd_rn(x2, off), __fadd_rn(y2, off));
            }
            __syncthreads();
        }

        // mask phase: rejection vs accepted set + intra-window pair masks
        {
            float4 myB;
            if (lane < take) myB = ldsPath ? preB[Ew + lane] : wb[lane];
            bool rej = false;
            if (lane < take) {
                for (int s2 = wave; s2 < count; s2 += 16) {
                    if (suppress(accB[s2], myB)) { rej = true; break; }
                }
            }
            u64 mask = __ballot(rej);
            if (lane == 0) sRej[wave] = mask;
            for (int rr = wave; rr < take; rr += 16) {
                float4 rB = ldsPath ? preB[Ew + rr] : wb[rr];
                bool sp = (lane < take && lane > rr) ? suppress(rB, myB) : false;
                u64 msk = __ballot(sp);
                if (lane == 0) wsup[rr] = msk;
            }
        }
        __syncthreads();

        // resolve (wave 0): union fast-path, else ctz-skipping greedy chain
        if (wave == 0) {
            u64 rj = (lane < 16) ? sRej[lane] : 0ull;
#pragma unroll
            for (int o = 1; o < 64; o <<= 1) rj |= __shfl_xor(rj, o);
            u64 supr = (lane < take) ? wsup[lane] : 0ull;
            u64 validb = (take >= 64) ? ~0ull : ((1ull << take) - 1ull);
            u64 aliveM = validb & ~rj;
            u64 contrib = ((aliveM >> lane) & 1ull) ? supr : 0ull;
            u64 U = contrib;
#pragma unroll
            for (int o = 1; o < 64; o <<= 1) U |= __shfl_xor(U, o);
            int space = NDET - count;
            u64 accM;
            if ((U & aliveM) == 0ull) {
                accM = aliveM;          // no alive element suppresses another
            } else {
                u64 rem = aliveM; accM = 0ull;
                while (rem) {
                    int rr = __builtin_ctzll(rem);
                    accM |= 1ull << rr;
                    if (__popcll(accM) >= space) break;   // further accepts never emitted
                    u64 sr = __shfl(supr, rr);
                    rem &= ~(1ull << rr);
                    rem &= ~sr;
                }
            }
            int na = __popcll(accM);
            int takeA = na < space ? na : space;
            if (lane < take && ((accM >> lane) & 1ull)) {
                int pos = __popcll(accM & ((1ull << lane) - 1ull));
                if (pos < takeA) {
                    int o2 = count + pos;
                    u64 key = skey[Ew + lane];
                    accB[o2] = ldsPath ? preB[Ew + lane] : wb[lane];
                    accR[o2] = ldsPath ? preR[Ew + lane] : wraw[lane];
                    accIdx[o2] = (int)(key & 0xFFFFFFFFu);
                    accS[o2] = unmapKm((u32)(key >> 32));
                }
            }
            if (lane == 0) s_count = count + takeA;
        }
        __syncthreads();
        count = s_count;
        Ew += take;
        if (count >= NDET) break;
    }
    __syncthreads();

    // emit top-100 (labels re-gathered, <=100 loads)
    for (int s2 = tid; s2 < NDET; s2 += 1024) {
        float4 bxv = make_float4(0.f, 0.f, 0.f, 0.f);
        float scv = 0.0f, lbv = -1.0f;
        if (s2 < count) {
            bxv = accR[s2];
            scv = accS[s2];
            lbv = (float)ml[accIdx[s2]];
        }
        ((float4*)out)[b * NDET + s2] = bxv;                                  // boxes [0,3200)
        out[BATCH * NDET * 4 + b * NDET + s2] = scv;                          // scores [3200,4000)
        out[BATCH * NDET * 4 + BATCH * NDET + b * NDET + s2] = lbv;           // labels [4000,4800)
    }
}

extern "C" void kernel_launch(void* const* d_in, const int* in_sizes, int n_in,
                              void* d_out, int out_size, void* d_ws, size_t ws_size,
                              hipStream_t stream) {
    (void)in_sizes; (void)n_in; (void)out_size; (void)ws_size;
    const float* logits  = (const float*)d_in[0];
    const float* reg     = (const float*)d_in[1];
    const float* ctr     = (const float*)d_in[2];
    const float* anchors = (const float*)d_in[3];
    float* out = (float*)d_out;

    char* ws = (char*)d_ws;
    size_t off = 0;
    auto alloc = [&](size_t bytes) -> void* {
        off = (off + 255) & ~(size_t)255;
        void* p = ws + off;
        off += bytes;
        return p;
    };
    float* mscore = (float*)alloc((size_t)BATCH * TOTAL * 4);
    int*   mlabel = (int*)  alloc((size_t)BATCH * TOTAL * 4);
    u32*   ghist  = (u32*)  alloc((size_t)(BATCH * NBUCK + 64) * 4);  // hist + done(strided) + pad
    u32*   done   = ghist + (size_t)BATCH * NBUCK;

    zero_hist<<<dim3((ZN + 255) / 256), 256, 0, stream>>>(ghist);
    fused_kernel<<<dim3(NBLK, BATCH), 1024, 0, stream>>>(
        logits, ctr, reg, anchors, mscore, mlabel, ghist, done, out);
}

// Round 8
// 127.022 us; speedup vs baseline: 1.3069x; 1.1807x over previous
//
#include <hip/hip_runtime.h>
#include <stdint.h>

typedef unsigned long long u64;
typedef unsigned int u32;

#define BATCH   8
#define TOTAL   21824
#define NCLS    80
#define NDET    100
#define IMGSZ   1024.0f
#define STHR    0.2f
#define NMST    0.6f
#define NBUCK   4096        /* coarse + fine bucket count */
#define BMAX    4031        /* last coarse bucket reachable by valid scores */
#define KGLOB   1000        /* global top-K prefix (== min per-level k) */
#define NLOC    22          /* ceil(TOTAL/1024) per-thread cached scores */
#define PRE     1024        /* precomputed sorted-prefix boxes in LDS */
#define ZN      ((BATCH * NBUCK) / 4)   /* uint4 count to zero */

__device__ __forceinline__ float sigm(float x) { return 1.0f / (1.0f + expf(-x)); }

// Order-preserving map: ascending km == descending score.
__device__ __forceinline__ u32 mapKm(float s) {
    u32 u = __float_as_uint(s);
    u32 m = u ^ ((u & 0x80000000u) ? 0xFFFFFFFFu : 0x80000000u);
    return ~m;
}
// Inverse for positive floats (all scattered scores are > 0.2):
__device__ __forceinline__ float unmapKm(u32 km) {
    return __uint_as_float((~km) ^ 0x80000000u);
}
// Composite key: ascending u64 == (score desc, anchor idx asc).
__device__ __forceinline__ u64 makeKey(float s, u32 idx) {
    return (((u64)mapKm(s)) << 32) | (u64)idx;
}

// Monotone coarse bucket for VALID scores (>0.2): clamped to [0, BMAX].
__device__ __forceinline__ int bucketOfV(float s) {
    int b = (int)(__fmul_rn(__fsub_rn(1.0f, s), 5040.0f));
    return b > BMAX ? BMAX : b;
}

// Bit-exact IoU suppression test (no FMA contraction).
__device__ __forceinline__ bool suppress(float4 a, float4 c) {
    float aa = __fmul_rn(fmaxf(__fsub_rn(a.z, a.x), 0.f), fmaxf(__fsub_rn(a.w, a.y), 0.f));
    float ac = __fmul_rn(fmaxf(__fsub_rn(c.z, c.x), 0.f), fmaxf(__fsub_rn(c.w, c.y), 0.f));
    float ltx = fmaxf(a.x, c.x), lty = fmaxf(a.y, c.y);
    float rbx = fminf(a.z, c.z), rby = fminf(a.w, c.w);
    float iw = fmaxf(__fsub_rn(rbx, ltx), 0.f), ih = fmaxf(__fsub_rn(rby, lty), 0.f);
    float inter = __fmul_rn(iw, ih);
    float uni = __fsub_rn(__fadd_rn(aa, ac), inter);
    float iou = __fdiv_rn(inter, fmaxf(uni, 1e-9f));
    return iou > NMST;
}

// ---------------- Kernel 0: zero per-batch histograms ----------------
__global__ __launch_bounds__(256) void zero_hist(u32* __restrict__ g) {
    int i = blockIdx.x * 256 + threadIdx.x;
    if (i < ZN) ((uint4*)g)[i] = make_uint4(0u, 0u, 0u, 0u);
}

// ---------------- Kernel 1: max-score only (no argmax), full load hoist ----------------
__global__ __launch_bounds__(256) void score_kernel(
        const float* __restrict__ logits, const float* __restrict__ ctr,
        float* __restrict__ mscore, u32* __restrict__ ghist) {
    const int b = blockIdx.y;
    const int tid = threadIdx.x;
    const int wave = tid >> 6, lane = tid & 63;
    const int g = lane >> 2, j = lane & 3;
    const int rowBase = blockIdx.x * 256 + wave * 64;

    int r[4]; bool valid[4];
#pragma unroll
    for (int t = 0; t < 4; t++) {
        int rr = rowBase + 16 * t + g;
        valid[t] = rr < TOTAL;
        r[t] = valid[t] ? rr : (TOTAL - 1);   // clamp: keep loads uniform, mask at store
    }
    // Issue ALL 24 loads before any consume (explicit registers -> ~20KB/wave in
    // flight; round-6 lesson: VGPR=44 meant ~2 loads in flight, latency-serial).
    float4 vv[20]; float cc[4];
#pragma unroll
    for (int t = 0; t < 4; t++) {
        const float* rowp = logits + ((size_t)b * TOTAL + r[t]) * NCLS + j * 4;
#pragma unroll
        for (int u = 0; u < 5; u++)
            vv[t * 5 + u] = *(const float4*)(rowp + u * 16);
    }
#pragma unroll
    for (int t = 0; t < 4; t++) cc[t] = ctr[(size_t)b * TOTAL + r[t]];

#pragma unroll
    for (int t = 0; t < 4; t++) {
        float m0 = -1e30f;
#pragma unroll
        for (int u = 0; u < 5; u++) {
            float4 v = vv[t * 5 + u];
            m0 = fmaxf(m0, fmaxf(fmaxf(v.x, v.y), fmaxf(v.z, v.w)));
        }
        // merge the 4 lanes covering this row
        m0 = fmaxf(m0, __shfl_xor(m0, 1));
        m0 = fmaxf(m0, __shfl_xor(m0, 2));
        if (valid[t] && j == 0) {
            float sc = sqrtf(sigm(m0) * sigm(cc[t]));
            bool pass = sc > STHR;
            mscore[(size_t)b * TOTAL + r[t]] = pass ? sc : -1.0f;
            if (pass) atomicAdd(&ghist[(size_t)b * NBUCK + bucketOfV(sc)], 1u);
        }
    }
}

// Recompute (max, argmax-first) for one row; returns label via ref.
__device__ __forceinline__ int rowLabel(const float4* __restrict__ row4) {
    float best = -1e30f;
#pragma unroll
    for (int k = 0; k < 20; k++) {
        float4 q = row4[k];
        best = fmaxf(best, fmaxf(fmaxf(q.x, q.y), fmaxf(q.z, q.w)));
    }
    int lb = -1;
#pragma unroll
    for (int k = 0; k < 20; k++) {
        float4 q = row4[k];     // reload: L1/L2-hot
        if (lb < 0) {
            if      (q.x == best) lb = 4 * k;
            else if (q.y == best) lb = 4 * k + 1;
            else if (q.z == best) lb = 4 * k + 2;
            else if (q.w == best) lb = 4 * k + 3;
        }
    }
    return lb;
}

// ---------------- Kernel 2: coarse scan -> FINE rebucket -> scatter/sort -> NMS ----------------
__global__ __launch_bounds__(1024) void nms_kernel(
        const float* __restrict__ mscore, const float* __restrict__ logits,
        const float* __restrict__ anchors, const float* __restrict__ reg,
        const u32* __restrict__ ghist, float* __restrict__ out) {
    __shared__ u64 skey[2048];      // fine-radix sorted keys
    __shared__ float4 preB[PRE];    // class-offset boxes of sorted prefix
    __shared__ u32 curbuf[NBUCK];   // fine hist/cursors; ALIASED as preR after scatter
    __shared__ int preL[PRE];       // labels of sorted prefix
    __shared__ u32 waveSum[16], waveOff[16];
    __shared__ u32 sh_B, sh_m;
    __shared__ int s_count;
    __shared__ float4 accB[NDET];   // class-offset boxes of accepted
    __shared__ float4 accR[NDET];   // raw boxes of accepted
    __shared__ float  accS[NDET];   // scores of accepted
    __shared__ int    accL[NDET];   // labels of accepted
    __shared__ float4 wb[64], wraw[64];   // fallback window (Ew beyond PRE)
    __shared__ int    wLab[64];
    __shared__ u64 wsup[64];
    __shared__ u64 sRej[16];

    const int b = blockIdx.x, tid = threadIdx.x;
    const int wave = tid >> 6, lane = tid & 63;
    const float* ms = mscore + (size_t)b * TOTAL;
    const float4* anch4 = (const float4*)anchors;
    const float4* reg4 = ((const float4*)reg) + (size_t)b * TOTAL;
    const float* lg = logits + (size_t)b * TOTAL * NCLS;

    // Coarse bucket counts (issued first).
    uint4 hv = ((const uint4*)(ghist + (size_t)b * NBUCK))[tid];

    // Register-resident score cache: fully unrolled, compile-time indices.
    float sv[NLOC];
#pragma unroll
    for (int k = 0; k < NLOC; k++) {
        int i = tid + (k << 10);
        sv[k] = (i < TOTAL) ? ms[i] : -1.0f;
    }

    // ---- coarse scan: locate boundary bucket Bstar and inclusive count m ----
    u32 h0 = hv.x, h1 = hv.y, h2 = hv.z, h3 = hv.w;
    u32 s = h0 + h1 + h2 + h3;
    u32 incl = s;
    for (int o = 1; o < 64; o <<= 1) {
        u32 t2 = (u32)__shfl_up((int)incl, o);
        if (lane >= o) incl += t2;
    }
    if (lane == 63) waveSum[wave] = incl;
    __syncthreads();
    if (tid == 0) {
        u32 acc = 0;
#pragma unroll
        for (int w = 0; w < 16; w++) { waveOff[w] = acc; acc += waveSum[w]; }
        sh_m = acc;                       // default: all valid (if < KGLOB valid)
        sh_B = (u32)BMAX;                 // sentinel boundary
        s_count = 0;
    }
    __syncthreads();
    {
        const u32 E = waveOff[wave] + incl - s;
        const u32 p1 = E + h0, p2 = p1 + h1, p3 = p2 + h2, p4 = p3 + h3;
        if      (E  < KGLOB && KGLOB <= p1) { sh_B = (u32)(4 * tid);     sh_m = p1; }
        else if (p1 < KGLOB && KGLOB <= p2) { sh_B = (u32)(4 * tid + 1); sh_m = p2; }
        else if (p2 < KGLOB && KGLOB <= p3) { sh_B = (u32)(4 * tid + 2); sh_m = p3; }
        else if (p3 < KGLOB && KGLOB <= p4) { sh_B = (u32)(4 * tid + 3); sh_m = p4; }
    }
    // zero the fine histogram while the boundary settles
    curbuf[tid] = 0; curbuf[tid + 1024] = 0; curbuf[tid + 2048] = 0; curbuf[tid + 3072] = 0;
    __syncthreads();
    const int Bstar = (int)sh_B;

    // ---- adaptive fine bucketing over exactly the candidate key range ----
    // Candidates: s > STHR && coarse bucket <= Bstar, i.e. s in (sLo, 1.0) with
    // sLo one full coarse-bucket below the exact boundary (float-rounding safe).
    const float sLo = 1.0f - (float)(Bstar + 2) * (1.0f / 5040.0f);
    const u32 kmMin = mapKm(1.0f);            // all candidate km are strictly > kmMin
    const u32 kmMax = mapKm(sLo);             // and <= kmMax
    const u32 range = kmMax - kmMin + 1u;
    int hib = 32 - __clz(range);
    const int fsh = hib > 12 ? hib - 12 : 0;  // monotone power-of-2 bin map

    // fine histogram of candidates
#pragma unroll
    for (int k = 0; k < NLOC; k++) {
        float s0 = sv[k];
        if (s0 > STHR && bucketOfV(s0) <= Bstar) {
            u32 fb = (mapKm(s0) - kmMin) >> fsh;
            if (fb > 4095u) fb = 4095u;
            atomicAdd(&curbuf[fb], 1u);
        }
    }
    __syncthreads();

    // fine scan: thread t owns fine buckets 4t..4t+3
    u32 f0 = curbuf[4 * tid], f1 = curbuf[4 * tid + 1],
        f2 = curbuf[4 * tid + 2], f3 = curbuf[4 * tid + 3];
    u32 fs = f0 + f1 + f2 + f3;
    u32 fincl = fs;
    for (int o = 1; o < 64; o <<= 1) {
        u32 t2 = (u32)__shfl_up((int)fincl, o);
        if (lane >= o) fincl += t2;
    }
    __syncthreads();                       // waveSum reuse hazard gate
    if (lane == 63) waveSum[wave] = fincl;
    __syncthreads();
    if (tid == 0) {
        u32 acc = 0;
#pragma unroll
        for (int w = 0; w < 16; w++) { waveOff[w] = acc; acc += waveSum[w]; }
    }
    __syncthreads();
    const u32 E2 = waveOff[wave] + fincl - fs;
    const u32 q1 = E2 + f0, q2 = q1 + f1, q3 = q2 + f2;
    curbuf[4 * tid]     = E2;
    curbuf[4 * tid + 1] = q1;
    curbuf[4 * tid + 2] = q2;
    curbuf[4 * tid + 3] = q3;
    __syncthreads();

    // fine scatter
#pragma unroll
    for (int k = 0; k < NLOC; k++) {
        float s0 = sv[k];
        if (s0 > STHR && bucketOfV(s0) <= Bstar) {
            u32 fb = (mapKm(s0) - kmMin) >> fsh;
            if (fb > 4095u) fb = 4095u;
            int pos = (int)atomicAdd(&curbuf[fb], 1u);
            if (pos < 2048) skey[pos] = makeKey(s0, (u32)(tid + (k << 10)));
        }
    }
    __syncthreads();
    float4* preR = (float4*)curbuf;        // cursors dead -> alias as preR

    // insertion sort per fine bucket (E[cnt]~0.6, max ~5 -> serial chain gone)
#pragma unroll
    for (int q = 0; q < 4; q++) {
        u32 cnt = (q == 0) ? f0 : (q == 1) ? f1 : (q == 2) ? f2 : f3;
        u32 lo0 = (q == 0) ? E2 : (q == 1) ? q1 : (q == 2) ? q2 : q3;
        if (cnt > 1) {
            int lo = (int)lo0;
            int hi = lo + (int)cnt; if (hi > 2048) hi = 2048;
            for (int i2 = lo + 1; i2 < hi; i2++) {
                u64 key = skey[i2];
                int j2 = i2 - 1;
                while (j2 >= lo && skey[j2] > key) { skey[j2 + 1] = skey[j2]; j2--; }
                skey[j2 + 1] = key;
            }
        }
    }
    __syncthreads();
    int m = (int)sh_m; if (m > 2048) m = 2048;
    const int Pm = m < PRE ? m : PRE;

    // Precompute boxes + labels for the sorted prefix — ONE parallel gather round.
    for (int p = tid; p < Pm; p += 1024) {
        u64 key = skey[p];
        int idx = (int)(key & 0xFFFFFFFFu);
        float4 a = anch4[idx];
        float4 r = reg4[idx];
        int lb = rowLabel((const float4*)(lg + (size_t)idx * NCLS));
        float cx = (a.x + a.z) * 0.5f;
        float cy = (a.y + a.w) * 0.5f;
        float x1 = fminf(fmaxf(cx - r.x, 0.0f), IMGSZ);
        float y1 = fminf(fmaxf(cy - r.y, 0.0f), IMGSZ);
        float x2 = fminf(fmaxf(cx + r.z, 0.0f), IMGSZ);
        float y2 = fminf(fmaxf(cy + r.w, 0.0f), IMGSZ);
        float off = (float)lb * (IMGSZ + 1.0f);
        preR[p] = make_float4(x1, y1, x2, y2);
        preB[p] = make_float4(__fadd_rn(x1, off), __fadd_rn(y1, off),
                              __fadd_rn(x2, off), __fadd_rn(y2, off));
        preL[p] = lb;
    }
    __syncthreads();

    // Windowed greedy NMS over the sorted prefix (LDS-resident fast path).
    int count = 0, Ew = 0;
    while (true) {
        int take = m - Ew; if (take > 64) take = 64;
        if (take <= 0) break;
        const bool ldsPath = (Ew + take <= Pm);

        if (!ldsPath) {
            // rare fallback: gather+compute this window into wb/wraw/wLab
            if (tid < take) {
                int idx = (int)(skey[Ew + tid] & 0xFFFFFFFFu);
                float4 a = anch4[idx];
                float4 r = reg4[idx];
                int lb = rowLabel((const float4*)(lg + (size_t)idx * NCLS));
                float cx = (a.x + a.z) * 0.5f;
                float cy = (a.y + a.w) * 0.5f;
                float x1 = fminf(fmaxf(cx - r.x, 0.0f), IMGSZ);
                float y1 = fminf(fmaxf(cy - r.y, 0.0f), IMGSZ);
                float x2 = fminf(fmaxf(cx + r.z, 0.0f), IMGSZ);
                float y2 = fminf(fmaxf(cy + r.w, 0.0f), IMGSZ);
                float off = (float)lb * (IMGSZ + 1.0f);
                wraw[tid] = make_float4(x1, y1, x2, y2);
                wb[tid] = make_float4(__fadd_rn(x1, off), __fadd_rn(y1, off),
                                      __fadd_rn(x2, off), __fadd_rn(y2, off));
                wLab[tid] = lb;
            }
            __syncthreads();
        }

        // mask phase: rejection vs accepted set + intra-window pair masks
        {
            float4 myB;
            if (lane < take) myB = ldsPath ? preB[Ew + lane] : wb[lane];
            bool rej = false;
            if (lane < take) {
                for (int s2 = wave; s2 < count; s2 += 16) {
                    if (suppress(accB[s2], myB)) { rej = true; break; }
                }
            }
            u64 mask = __ballot(rej);
            if (lane == 0) sRej[wave] = mask;
            for (int rr = wave; rr < take; rr += 16) {
                float4 rB = ldsPath ? preB[Ew + rr] : wb[rr];
                bool sp = (lane < take && lane > rr) ? suppress(rB, myB) : false;
                u64 msk = __ballot(sp);
                if (lane == 0) wsup[rr] = msk;
            }
        }
        __syncthreads();

        // resolve (wave 0): union fast-path, else ctz-skipping greedy chain
        if (wave == 0) {
            u64 rj = (lane < 16) ? sRej[lane] : 0ull;
#pragma unroll
            for (int o = 1; o < 64; o <<= 1) rj |= __shfl_xor(rj, o);
            u64 supr = (lane < take) ? wsup[lane] : 0ull;
            u64 validb = (take >= 64) ? ~0ull : ((1ull << take) - 1ull);
            u64 aliveM = validb & ~rj;
            u64 contrib = ((aliveM >> lane) & 1ull) ? supr : 0ull;
            u64 U = contrib;
#pragma unroll
            for (int o = 1; o < 64; o <<= 1) U |= __shfl_xor(U, o);
            int space = NDET - count;
            u64 accM;
            if ((U & aliveM) == 0ull) {
                accM = aliveM;          // no alive element suppresses another
            } else {
                u64 rem = aliveM; accM = 0ull;
                while (rem) {
                    int rr = __builtin_ctzll(rem);
                    accM |= 1ull << rr;
                    if (__popcll(accM) >= space) break;   // further accepts never emitted
                    u64 sr = __shfl(supr, rr);
                    rem &= ~(1ull << rr);
                    rem &= ~sr;
                }
            }
            int na = __popcll(accM);
            int takeA = na < space ? na : space;
            if (lane < take && ((accM >> lane) & 1ull)) {
                int pos = __popcll(accM & ((1ull << lane) - 1ull));
                if (pos < takeA) {
                    int o2 = count + pos;
                    u64 key = skey[Ew + lane];
                    accB[o2] = ldsPath ? preB[Ew + lane] : wb[lane];
                    accR[o2] = ldsPath ? preR[Ew + lane] : wraw[lane];
                    accL[o2] = ldsPath ? preL[Ew + lane] : wLab[lane];
                    accS[o2] = unmapKm((u32)(key >> 32));
                }
            }
            if (lane == 0) s_count = count + takeA;
        }
        __syncthreads();
        count = s_count;
        Ew += take;
        if (count >= NDET) break;
    }
    __syncthreads();

    // emit top-100 (pure LDS)
    for (int s2 = tid; s2 < NDET; s2 += 1024) {
        float4 bxv = make_float4(0.f, 0.f, 0.f, 0.f);
        float scv = 0.0f, lbv = -1.0f;
        if (s2 < count) {
            bxv = accR[s2];
            scv = accS[s2];
            lbv = (float)accL[s2];
        }
        ((float4*)out)[b * NDET + s2] = bxv;                                  // boxes [0,3200)
        out[BATCH * NDET * 4 + b * NDET + s2] = scv;                          // scores [3200,4000)
        out[BATCH * NDET * 4 + BATCH * NDET + b * NDET + s2] = lbv;           // labels [4000,4800)
    }
}

extern "C" void kernel_launch(void* const* d_in, const int* in_sizes, int n_in,
                              void* d_out, int out_size, void* d_ws, size_t ws_size,
                              hipStream_t stream) {
    (void)in_sizes; (void)n_in; (void)out_size; (void)ws_size;
    const float* logits  = (const float*)d_in[0];
    const float* reg     = (const float*)d_in[1];
    const float* ctr     = (const float*)d_in[2];
    const float* anchors = (const float*)d_in[3];
    float* out = (float*)d_out;

    char* ws = (char*)d_ws;
    size_t off = 0;
    auto alloc = [&](size_t bytes) -> void* {
        off = (off + 255) & ~(size_t)255;
        void* p = ws + off;
        off += bytes;
        return p;
    };
    float* mscore = (float*)alloc((size_t)BATCH * TOTAL * 4);
    u32*   ghist  = (u32*)  alloc((size_t)BATCH * NBUCK * 4);

    zero_hist<<<dim3((ZN + 255) / 256), 256, 0, stream>>>(ghist);
    score_kernel<<<dim3((TOTAL + 255) / 256, BATCH), 256, 0, stream>>>(logits, ctr, mscore, ghist);
    nms_kernel<<<BATCH, 1024, 0, stream>>>(mscore, logits, anchors, reg, ghist, out);
}